// Round 5
// baseline (187.877 us; speedup 1.0000x reference)
//
#include <hip/hip_runtime.h>
#include <math.h>

// Problem constants (reference: B=4, N=2048, H=5, L=3)
#define B_ 4
#define N_ 2048
#define H_ 5
#define L_ 3
#define EPS_ 1e-6f

constexpr int RPW = 4;             // rows per wave (register-tiled)
constexpr int WAVES = 4;           // waves per block (256 threads)
constexpr int RPB = RPW * WAVES;   // rows per block = 16
constexpr int CHUNKS = N_ / RPB;   // 128 blocks per batch row
constexpr int GRID = B_ * CHUNKS;  // 512 blocks (2/CU -> all co-resident)
constexpr int ITERS = N_ / 64;     // 32 j-elements per lane
constexpr float LOG2E = 1.4426950408889634f;

// Workspace layout (floats)
//   a[l]    : 3 x [B,N]        attention outputs
//   part[l] : 3 x [B,CHUNKS]   (sum,sumsq) float2 partials
//   ctrs    : 3 barrier counters (zeroed via hipMemsetAsync each launch)
#define WS_A(l)    (ws + (l) * (B_ * N_))
#define WS_PART(l) ((float2*)(ws + 3 * B_ * N_) + (l) * (B_ * CHUNKS))
#define WS_CTR_OFF (3 * B_ * N_ + 3 * B_ * CHUNKS * 2)   // float offset
// each counter on its own 256B line
#define CTR(l) ((unsigned*)(ws + WS_CTR_OFF) + (l) * 64)

// Device-scope counting barrier (all GRID blocks co-resident; no cg, so the
// compiler keeps the per-lane register cache intact).
__device__ __forceinline__ void grid_barrier(unsigned* ctr) {
  __syncthreads();
  if (threadIdx.x == 0) {
    __threadfence();                       // release: publish a/part writes
    atomicAdd(ctr, 1u);                    // device-scope by default
    while (__hip_atomic_load(ctr, __ATOMIC_RELAXED,
                             __HIP_MEMORY_SCOPE_AGENT) < (unsigned)GRID) {
      __builtin_amdgcn_s_sleep(1);
    }
    __threadfence();                       // acquire: see others' writes
  }
  __syncthreads();
}

// Whole 3-layer encoder, one dispatch. Residual row lives in LDS (xb) the
// entire time. Per layer: rank-1-score attention -> a[l] + partials -> grid
// barrier -> every block redundantly reduces partials and applies
// xb += gamma*(a-mean)/(sqrt(var_ub)+eps)+beta (last layer: write out chunk).
__global__ __launch_bounds__(256) void fused_encoder_kernel(
    const float* __restrict__ x,      // [B,N]
    const float* __restrict__ WQ,     // [L,H,N]
    const float* __restrict__ WK,     // [L,H,N]
    const float* __restrict__ WV,     // [L,H,N]
    const float* __restrict__ W0,     // [L,H]
    const float* __restrict__ gamma,  // [N]
    const float* __restrict__ beta,   // [N]
    float* __restrict__ out,          // [B,N]
    float* __restrict__ ws)
{
  __shared__ float xb[N_];     // residual row (8 KB), persists across layers
  __shared__ float2 kv[N_];    // (k'_j, v_j) current head (16 KB)
  __shared__ float2 red4[WAVES];

  const int bid = blockIdx.x;
  const int b = bid / CHUNKS;
  const int chunk = bid % CHUNKS;
  const int i0 = chunk * RPB;
  const int tid = threadIdx.x;
  const int wave = tid >> 6;
  const int lane = tid & 63;

  // Stage the residual row once; it stays in LDS for all 3 layers.
  for (int j = tid; j < N_; j += 256) xb[j] = x[b * N_ + j];

  for (int l = 0; l < L_; ++l) {
    const float* wq = WQ + l * H_ * N_;
    const float* wk = WK + l * H_ * N_;
    const float* wv = WV + l * H_ * N_;
    const float* w0 = W0 + l * H_;
    float* a_out = WS_A(l);
    float2* part_out = WS_PART(l);

    float acc[RPW];
#pragma unroll
    for (int r = 0; r < RPW; ++r) acc[r] = 0.f;

    for (int h = 0; h < H_; ++h) {
      __syncthreads();  // xb staged / previous kv readers done
      for (int j = tid; j < N_; j += 256) {
        float oj = xb[j];
        kv[j] = make_float2(oj * wk[h * N_ + j] * LOG2E, oj * wv[h * N_ + j]);
      }
      __syncthreads();

      // Register-cache this lane's 32 (k',v) pairs
      float kx[ITERS], ky[ITERS];
#pragma unroll
      for (int it = 0; it < ITERS; ++it) {
        float2 t = kv[it * 64 + lane];
        kx[it] = t.x;
        ky[it] = t.y;
      }

      float s[RPW], d[RPW], n[RPW];
#pragma unroll
      for (int r = 0; r < RPW; ++r) {
        const int i = i0 + wave * RPW + r;
        s[r] = xb[i] * wq[h * N_ + i];
        d[r] = 0.f;
        n[r] = 0.f;
      }

#pragma unroll
      for (int it = 0; it < ITERS; ++it) {
#pragma unroll
        for (int r = 0; r < RPW; ++r) {
          float e = __builtin_amdgcn_exp2f(s[r] * kx[it]);
          d[r] += e;
          n[r] = fmaf(e, ky[it], n[r]);
        }
      }

      const float w0h = w0[h];
#pragma unroll
      for (int r = 0; r < RPW; ++r) {
        float dd = d[r], nn = n[r];
#pragma unroll
        for (int off = 32; off; off >>= 1) {
          dd += __shfl_xor(dd, off);
          nn += __shfl_xor(nn, off);
        }
        const int i = i0 + wave * RPW + r;
        float2 kvi = kv[i];
        float ed = __builtin_amdgcn_exp2f(s[r] * kvi.x);  // diagonal term
        acc[r] = fmaf(w0h, (nn - ed * kvi.y) / dd, acc[r]);
      }
    }

    // Publish a[l] chunk + (sum,sumsq) partial
    if (lane == 0) {
      float s1 = 0.f, s2 = 0.f;
#pragma unroll
      for (int r = 0; r < RPW; ++r) {
        a_out[b * N_ + i0 + wave * RPW + r] = acc[r];
        s1 += acc[r];
        s2 = fmaf(acc[r], acc[r], s2);
      }
      red4[wave] = make_float2(s1, s2);
    }
    __syncthreads();
    if (tid == 0) {
      float2 t = red4[0];
      t.x += red4[1].x + red4[2].x + red4[3].x;
      t.y += red4[1].y + red4[2].y + red4[3].y;
      part_out[b * CHUNKS + chunk] = t;
    }

    grid_barrier(CTR(l));

    // Reduce the 128 partials for this batch row (redundant per wave)
    float2 p0 = part_out[b * CHUNKS + lane];
    float2 p1 = part_out[b * CHUNKS + 64 + lane];
    float s1 = p0.x + p1.x;
    float s2 = p0.y + p1.y;
#pragma unroll
    for (int off = 32; off; off >>= 1) {
      s1 += __shfl_xor(s1, off);
      s2 += __shfl_xor(s2, off);
    }
    const float mean = s1 * (1.f / N_);
    const float var = (s2 - s1 * mean) * (1.f / (N_ - 1));
    const float inv = 1.f / (sqrtf(var) + EPS_);

    if (l < L_ - 1) {
      // xb += LN(a[l])  (full row, redundant across the row's blocks)
      for (int j = tid; j < N_; j += 256) {
        float aj = a_out[b * N_ + j];
        xb[j] += gamma[j] * (aj - mean) * inv + beta[j];
      }
      // next head-loop iteration starts with __syncthreads()
    } else {
      // Final LN: owner block writes its chunk of out
      if (tid < RPB) {
        const int i = i0 + tid;
        out[b * N_ + i] =
            xb[i] + gamma[i] * (a_out[b * N_ + i] - mean) * inv + beta[i];
      }
    }
  }
}

extern "C" void kernel_launch(void* const* d_in, const int* in_sizes, int n_in,
                              void* d_out, int out_size, void* d_ws, size_t ws_size,
                              hipStream_t stream) {
  const float* x     = (const float*)d_in[0];
  const float* WQ    = (const float*)d_in[1];
  const float* WK    = (const float*)d_in[2];
  const float* WV    = (const float*)d_in[3];
  const float* W0    = (const float*)d_in[4];
  const float* gamma = (const float*)d_in[5];
  const float* beta  = (const float*)d_in[6];
  float* out = (float*)d_out;
  float* ws  = (float*)d_ws;

  // Zero the barrier counters (deterministic per launch; capture-safe)
  hipMemsetAsync((void*)CTR(0), 0, 3 * 64 * sizeof(unsigned), stream);

  fused_encoder_kernel<<<GRID, 256, 0, stream>>>(
      x, WQ, WK, WV, W0, gamma, beta, out, ws);
}

// Round 6
// 74.728 us; speedup vs baseline: 2.5141x; 2.5141x over previous
//
#include <hip/hip_runtime.h>
#include <math.h>

// Problem constants (reference: B=4, N=2048, H=5, L=3)
#define B_ 4
#define N_ 2048
#define H_ 5
#define L_ 3
#define EPS_ 1e-6f

constexpr int RPW = 4;             // rows per wave (register-tiled)
constexpr int WAVES = 4;           // waves per block (256 threads)
constexpr int RPB = RPW * WAVES;   // rows per block = 16
constexpr int CHUNKS = N_ / RPB;   // 128 blocks per batch row
constexpr int ITERS = N_ / 64;     // 32 j-elements per lane
constexpr float LOG2E = 1.4426950408889634f;

// Attention for one layer, with the PREVIOUS layer's LayerNorm folded in.
// The per-lane (k',v) cache is PINNED into VGPRs via empty inline-asm "+v"
// operands -- without this the compiler rematerializes the LDS reads at
// every use (R3/R5 showed VGPR_Count 56/80: cache demoted, 4x LDS traffic).
__global__ __launch_bounds__(256) void attn_layer_kernel(
    const float* __restrict__ res_in,     // [B,N] residual entering this layer
    const float* __restrict__ a_prev,     // [B,N] previous attention out (null for l=0)
    const float2* __restrict__ part_prev, // [B,CHUNKS] (sum,sumsq) of a_prev
    const float* __restrict__ gamma,      // [N]
    const float* __restrict__ beta,       // [N]
    const float* __restrict__ wq,         // [H,N] layer slice
    const float* __restrict__ wk,         // [H,N]
    const float* __restrict__ wv,         // [H,N]
    const float* __restrict__ w0,         // [H]
    float* __restrict__ a_out,            // [B,N]
    float2* __restrict__ part_out,        // [B,CHUNKS]
    float* __restrict__ res_out)          // [B,N] updated residual (null for l=0)
{
  __shared__ float xb[N_];     // current residual row (8 KB)
  __shared__ float2 kv[N_];    // (k'_j, v_j) for current head (16 KB)
  __shared__ float2 red4[WAVES];

  const int bid = blockIdx.x;
  const int b = bid / CHUNKS;
  const int chunk = bid % CHUNKS;
  const int i0 = chunk * RPB;
  const int tid = threadIdx.x;
  const int wave = tid >> 6;
  const int lane = tid & 63;

  // ---- Stage cur row into LDS (folding previous LN if present) ----
  if (a_prev == nullptr) {
    for (int j = tid; j < N_; j += 256) xb[j] = res_in[b * N_ + j];
  } else {
    float2 p0 = part_prev[b * CHUNKS + lane];
    float2 p1 = part_prev[b * CHUNKS + 64 + lane];
    float s1 = p0.x + p1.x;
    float s2 = p0.y + p1.y;
#pragma unroll
    for (int off = 32; off; off >>= 1) {
      s1 += __shfl_xor(s1, off);
      s2 += __shfl_xor(s2, off);
    }
    const float mean = s1 * (1.f / N_);
    const float var = (s2 - s1 * mean) * (1.f / (N_ - 1));
    const float inv = 1.f / (sqrtf(var) + EPS_);
    for (int j = tid; j < N_; j += 256) {
      float r = res_in[b * N_ + j];
      float aj = a_prev[b * N_ + j];
      xb[j] = r + gamma[j] * (aj - mean) * inv + beta[j];
    }
  }
  __syncthreads();

  // Publish this block's chunk of the updated residual for the NEXT dispatch
  if (res_out != nullptr && tid < RPB)
    res_out[b * N_ + i0 + tid] = xb[i0 + tid];

  // ---- Attention (register-tiled, rank-1 scores) ----
  float acc[RPW];
#pragma unroll
  for (int r = 0; r < RPW; ++r) acc[r] = 0.f;

  for (int h = 0; h < H_; ++h) {
    if (h) __syncthreads();  // previous head's kv readers done
    for (int j = tid; j < N_; j += 256) {
      float oj = xb[j];
      kv[j] = make_float2(oj * wk[h * N_ + j] * LOG2E, oj * wv[h * N_ + j]);
    }
    __syncthreads();

    // Register-cache this lane's 32 (k',v) pairs -- PINNED in VGPRs
    float kx[ITERS], ky[ITERS];
#pragma unroll
    for (int it = 0; it < ITERS; ++it) {
      float2 t = kv[it * 64 + lane];
      kx[it] = t.x;
      ky[it] = t.y;
      asm volatile("" : "+v"(kx[it]), "+v"(ky[it]));  // forbid LDS remat
    }

    float s[RPW], d[RPW], n[RPW];
#pragma unroll
    for (int r = 0; r < RPW; ++r) {
      const int i = i0 + wave * RPW + r;
      s[r] = xb[i] * wq[h * N_ + i];
      d[r] = 0.f;
      n[r] = 0.f;
    }

#pragma unroll
    for (int it = 0; it < ITERS; ++it) {
#pragma unroll
      for (int r = 0; r < RPW; ++r) {
        float e = __builtin_amdgcn_exp2f(s[r] * kx[it]);
        d[r] += e;
        n[r] = fmaf(e, ky[it], n[r]);
      }
    }

    const float w0h = w0[h];
#pragma unroll
    for (int r = 0; r < RPW; ++r) {
      float dd = d[r], nn = n[r];
#pragma unroll
      for (int off = 32; off; off >>= 1) {
        dd += __shfl_xor(dd, off);
        nn += __shfl_xor(nn, off);
      }
      const int i = i0 + wave * RPW + r;
      float2 kvi = kv[i];
      float ed = __builtin_amdgcn_exp2f(s[r] * kvi.x);  // diagonal term
      acc[r] = fmaf(w0h, (nn - ed * kvi.y) * __builtin_amdgcn_rcpf(dd), acc[r]);
    }
  }

  // ---- Outputs: a_out chunk + (sum,sumsq) partial ----
  if (lane == 0) {
    float s1 = 0.f, s2 = 0.f;
#pragma unroll
    for (int r = 0; r < RPW; ++r) {
      a_out[b * N_ + i0 + wave * RPW + r] = acc[r];
      s1 += acc[r];
      s2 = fmaf(acc[r], acc[r], s2);
    }
    red4[wave] = make_float2(s1, s2);
  }
  __syncthreads();
  if (tid == 0) {
    float2 t = red4[0];
    t.x += red4[1].x + red4[2].x + red4[3].x;
    t.y += red4[1].y + red4[2].y + red4[3].y;
    part_out[b * CHUNKS + chunk] = t;
  }
}

// out[b,:] = res_in + gamma*(a-mean)/(sqrt(var_unbiased)+eps) + beta
__global__ __launch_bounds__(256) void final_ln_kernel(
    const float* __restrict__ res_in, const float* __restrict__ a_prev,
    const float2* __restrict__ part_prev, const float* __restrict__ gamma,
    const float* __restrict__ beta, float* __restrict__ out)
{
  const int b = blockIdx.x;
  const int tid = threadIdx.x;
  const int lane = tid & 63;

  float2 p0 = part_prev[b * CHUNKS + lane];
  float2 p1 = part_prev[b * CHUNKS + 64 + lane];
  float s1 = p0.x + p1.x;
  float s2 = p0.y + p1.y;
#pragma unroll
  for (int off = 32; off; off >>= 1) {
    s1 += __shfl_xor(s1, off);
    s2 += __shfl_xor(s2, off);
  }
  const float mean = s1 * (1.f / N_);
  const float var = (s2 - s1 * mean) * (1.f / (N_ - 1));
  const float inv = 1.f / (sqrtf(var) + EPS_);

  for (int j = tid; j < N_; j += 256) {
    out[b * N_ + j] =
        res_in[b * N_ + j] + gamma[j] * (a_prev[b * N_ + j] - mean) * inv + beta[j];
  }
}

extern "C" void kernel_launch(void* const* d_in, const int* in_sizes, int n_in,
                              void* d_out, int out_size, void* d_ws, size_t ws_size,
                              hipStream_t stream) {
  const float* x     = (const float*)d_in[0];
  const float* WQ    = (const float*)d_in[1];  // [L,H,N]
  const float* WK    = (const float*)d_in[2];
  const float* WV    = (const float*)d_in[3];
  const float* W0    = (const float*)d_in[4];  // [L,H]
  const float* gamma = (const float*)d_in[5];
  const float* beta  = (const float*)d_in[6];
  float* out = (float*)d_out;

  float* ws = (float*)d_ws;
  float* a0 = ws;                 // [B,N]
  float* a1 = ws + 8192;          // [B,N]
  float* a2 = ws + 16384;         // [B,N]
  float* res1 = ws + 24576;       // [B,N]
  float* res2 = ws + 32768;       // [B,N]
  float2* p0 = (float2*)(ws + 40960);  // [B,CHUNKS]
  float2* p1 = (float2*)(ws + 43008);  // [B,CHUNKS]
  float2* p2 = (float2*)(ws + 45056);  // [B,CHUNKS]

  const int G = B_ * CHUNKS;  // 512 blocks

  attn_layer_kernel<<<G, 256, 0, stream>>>(
      x, nullptr, nullptr, gamma, beta,
      WQ, WK, WV, W0, a0, p0, nullptr);
  attn_layer_kernel<<<G, 256, 0, stream>>>(
      x, a0, p0, gamma, beta,
      WQ + H_ * N_, WK + H_ * N_, WV + H_ * N_, W0 + H_, a1, p1, res1);
  attn_layer_kernel<<<G, 256, 0, stream>>>(
      res1, a1, p1, gamma, beta,
      WQ + 2 * H_ * N_, WK + 2 * H_ * N_, WV + 2 * H_ * N_, W0 + 2 * H_, a2, p2, res2);
  final_ln_kernel<<<B_, 256, 0, stream>>>(res2, a2, p2, gamma, beta, out);
}

// Round 7
// 68.799 us; speedup vs baseline: 2.7308x; 1.0862x over previous
//
#include <hip/hip_runtime.h>
#include <math.h>

// Problem constants (reference: B=4, N=2048, H=5, L=3)
#define B_ 4
#define N_ 2048
#define H_ 5
#define L_ 3
#define EPS_ 1e-6f

constexpr int RPW = 2;             // rows per wave
constexpr int WAVES = 8;           // waves per block (512 threads)
constexpr int THREADS = WAVES * 64;
constexpr int RPB = RPW * WAVES;   // rows per block = 16
constexpr int CHUNKS = N_ / RPB;   // 128 blocks per batch row
constexpr int ITERS = N_ / 64;     // 32 j-elements per lane
constexpr float LOG2E = 1.4426950408889634f;

// Attention for one layer, with the PREVIOUS layer's LayerNorm folded in.
// 8 waves/block at 2 blocks/CU -> 4 waves/SIMD for latency hiding (R6 was 2).
__global__ __launch_bounds__(THREADS) void attn_layer_kernel(
    const float* __restrict__ res_in,     // [B,N] residual entering this layer
    const float* __restrict__ a_prev,     // [B,N] previous attention out (null for l=0)
    const float2* __restrict__ part_prev, // [B,CHUNKS] (sum,sumsq) of a_prev
    const float* __restrict__ gamma,      // [N]
    const float* __restrict__ beta,       // [N]
    const float* __restrict__ wq,         // [H,N] layer slice
    const float* __restrict__ wk,         // [H,N]
    const float* __restrict__ wv,         // [H,N]
    const float* __restrict__ w0,         // [H]
    float* __restrict__ a_out,            // [B,N]
    float2* __restrict__ part_out,        // [B,CHUNKS]
    float* __restrict__ res_out)          // [B,N] updated residual (null for l=0)
{
  __shared__ float xb[N_];     // current residual row (8 KB)
  __shared__ float2 kv[N_];    // (k'_j, v_j) for current head (16 KB)
  __shared__ float2 red4[WAVES];

  const int bid = blockIdx.x;
  const int b = bid / CHUNKS;
  const int chunk = bid % CHUNKS;
  const int i0 = chunk * RPB;
  const int tid = threadIdx.x;
  const int wave = tid >> 6;
  const int lane = tid & 63;

  // ---- Stage cur row into LDS (folding previous LN if present) ----
  if (a_prev == nullptr) {
    for (int j = tid; j < N_; j += THREADS) xb[j] = res_in[b * N_ + j];
  } else {
    float2 p0 = part_prev[b * CHUNKS + lane];
    float2 p1 = part_prev[b * CHUNKS + 64 + lane];
    float s1 = p0.x + p1.x;
    float s2 = p0.y + p1.y;
#pragma unroll
    for (int off = 32; off; off >>= 1) {
      s1 += __shfl_xor(s1, off);
      s2 += __shfl_xor(s2, off);
    }
    const float mean = s1 * (1.f / N_);
    const float var = (s2 - s1 * mean) * (1.f / (N_ - 1));
    const float inv = 1.f / (sqrtf(var) + EPS_);
    for (int j = tid; j < N_; j += THREADS) {
      float r = res_in[b * N_ + j];
      float aj = a_prev[b * N_ + j];
      xb[j] = r + gamma[j] * (aj - mean) * inv + beta[j];
    }
  }
  __syncthreads();

  // Publish this block's chunk of the updated residual for the NEXT dispatch
  if (res_out != nullptr && tid < RPB)
    res_out[b * N_ + i0 + tid] = xb[i0 + tid];

  // ---- Attention (rank-1 scores) ----
  float acc[RPW];
#pragma unroll
  for (int r = 0; r < RPW; ++r) acc[r] = 0.f;

  for (int h = 0; h < H_; ++h) {
    if (h) __syncthreads();  // previous head's kv readers done
    for (int j = tid; j < N_; j += THREADS) {
      float oj = xb[j];
      kv[j] = make_float2(oj * wk[h * N_ + j] * LOG2E, oj * wv[h * N_ + j]);
    }
    __syncthreads();

    float s[RPW], d[RPW], n[RPW];
#pragma unroll
    for (int r = 0; r < RPW; ++r) {
      const int i = i0 + wave * RPW + r;
      s[r] = xb[i] * wq[h * N_ + i];
      d[r] = 0.f;
      n[r] = 0.f;
    }

#pragma unroll
    for (int it = 0; it < ITERS; ++it) {
      float2 kvj = kv[it * 64 + lane];
#pragma unroll
      for (int r = 0; r < RPW; ++r) {
        float e = __builtin_amdgcn_exp2f(s[r] * kvj.x);
        d[r] += e;
        n[r] = fmaf(e, kvj.y, n[r]);
      }
    }

    const float w0h = w0[h];
#pragma unroll
    for (int r = 0; r < RPW; ++r) {
      float dd = d[r], nn = n[r];
#pragma unroll
      for (int off = 32; off; off >>= 1) {
        dd += __shfl_xor(dd, off);
        nn += __shfl_xor(nn, off);
      }
      const int i = i0 + wave * RPW + r;
      float2 kvi = kv[i];
      float ed = __builtin_amdgcn_exp2f(s[r] * kvi.x);  // diagonal term
      acc[r] = fmaf(w0h, (nn - ed * kvi.y) * __builtin_amdgcn_rcpf(dd), acc[r]);
    }
  }

  // ---- Outputs: a_out chunk + (sum,sumsq) partial ----
  if (lane == 0) {
    float s1 = 0.f, s2 = 0.f;
#pragma unroll
    for (int r = 0; r < RPW; ++r) {
      a_out[b * N_ + i0 + wave * RPW + r] = acc[r];
      s1 += acc[r];
      s2 = fmaf(acc[r], acc[r], s2);
    }
    red4[wave] = make_float2(s1, s2);
  }
  __syncthreads();
  if (tid == 0) {
    float2 t = red4[0];
#pragma unroll
    for (int w = 1; w < WAVES; ++w) {
      t.x += red4[w].x;
      t.y += red4[w].y;
    }
    part_out[b * CHUNKS + chunk] = t;
  }
}

// out[b,:] = res_in + gamma*(a-mean)/(sqrt(var_unbiased)+eps) + beta
__global__ __launch_bounds__(256) void final_ln_kernel(
    const float* __restrict__ res_in, const float* __restrict__ a_prev,
    const float2* __restrict__ part_prev, const float* __restrict__ gamma,
    const float* __restrict__ beta, float* __restrict__ out)
{
  const int b = blockIdx.x;
  const int tid = threadIdx.x;
  const int lane = tid & 63;

  float2 p0 = part_prev[b * CHUNKS + lane];
  float2 p1 = part_prev[b * CHUNKS + 64 + lane];
  float s1 = p0.x + p1.x;
  float s2 = p0.y + p1.y;
#pragma unroll
  for (int off = 32; off; off >>= 1) {
    s1 += __shfl_xor(s1, off);
    s2 += __shfl_xor(s2, off);
  }
  const float mean = s1 * (1.f / N_);
  const float var = (s2 - s1 * mean) * (1.f / (N_ - 1));
  const float inv = 1.f / (sqrtf(var) + EPS_);

  for (int j = tid; j < N_; j += 256) {
    out[b * N_ + j] =
        res_in[b * N_ + j] + gamma[j] * (a_prev[b * N_ + j] - mean) * inv + beta[j];
  }
}

extern "C" void kernel_launch(void* const* d_in, const int* in_sizes, int n_in,
                              void* d_out, int out_size, void* d_ws, size_t ws_size,
                              hipStream_t stream) {
  const float* x     = (const float*)d_in[0];
  const float* WQ    = (const float*)d_in[1];  // [L,H,N]
  const float* WK    = (const float*)d_in[2];
  const float* WV    = (const float*)d_in[3];
  const float* W0    = (const float*)d_in[4];  // [L,H]
  const float* gamma = (const float*)d_in[5];
  const float* beta  = (const float*)d_in[6];
  float* out = (float*)d_out;

  float* ws = (float*)d_ws;
  float* a0 = ws;                 // [B,N]
  float* a1 = ws + 8192;          // [B,N]
  float* a2 = ws + 16384;         // [B,N]
  float* res1 = ws + 24576;       // [B,N]
  float* res2 = ws + 32768;       // [B,N]
  float2* p0 = (float2*)(ws + 40960);  // [B,CHUNKS]
  float2* p1 = (float2*)(ws + 43008);  // [B,CHUNKS]
  float2* p2 = (float2*)(ws + 45056);  // [B,CHUNKS]

  const int G = B_ * CHUNKS;  // 512 blocks

  attn_layer_kernel<<<G, THREADS, 0, stream>>>(
      x, nullptr, nullptr, gamma, beta,
      WQ, WK, WV, W0, a0, p0, nullptr);
  attn_layer_kernel<<<G, THREADS, 0, stream>>>(
      x, a0, p0, gamma, beta,
      WQ + H_ * N_, WK + H_ * N_, WV + H_ * N_, W0 + H_, a1, p1, res1);
  attn_layer_kernel<<<G, THREADS, 0, stream>>>(
      res1, a1, p1, gamma, beta,
      WQ + 2 * H_ * N_, WK + 2 * H_ * N_, WV + 2 * H_ * N_, W0 + 2 * H_, a2, p2, res2);
  final_ln_kernel<<<B_, 256, 0, stream>>>(res2, a2, p2, gamma, beta, out);
}

// Round 8
// 64.884 us; speedup vs baseline: 2.8956x; 1.0603x over previous
//
#include <hip/hip_runtime.h>
#include <math.h>

// Problem constants (reference: B=4, N=2048, H=5, L=3)
#define B_ 4
#define N_ 2048
#define H_ 5
#define L_ 3
#define EPS_ 1e-6f

constexpr int RPW = 2;             // rows per wave
constexpr int WAVES = 8;           // waves per block (512 threads)
constexpr int THREADS = WAVES * 64;
constexpr int RPB = RPW * WAVES;   // rows per block = 16
constexpr int CHUNKS = N_ / RPB;   // 128 blocks per batch row
constexpr int ITERS = N_ / 64;     // 32 j-elements per lane
constexpr int SIT = N_ / THREADS;  // 4 staging iters per thread
constexpr float LOG2E = 1.4426950408889634f;

// Attention layer with previous LN folded in, software-pipelined heads:
// per head: issue next head's wk/wv/wq loads -> inner exp loop on cur LDS
// buffer -> write next head's kv to other buffer -> reduce -> ONE barrier.
// Global-load latency hides under the inner loop instead of being exposed
// at a block-wide barrier (R7's structure exposed it 10x per layer).
__global__ __launch_bounds__(THREADS) void attn_layer_kernel(
    const float* __restrict__ res_in,     // [B,N]
    const float* __restrict__ a_prev,     // [B,N] (null for l=0)
    const float2* __restrict__ part_prev, // [B,CHUNKS]
    const float* __restrict__ gamma,      // [N]
    const float* __restrict__ beta,       // [N]
    const float* __restrict__ wq,         // [H,N]
    const float* __restrict__ wk,         // [H,N]
    const float* __restrict__ wv,         // [H,N]
    const float* __restrict__ w0,         // [H]
    float* __restrict__ a_out,            // [B,N]
    float2* __restrict__ part_out,        // [B,CHUNKS]
    float* __restrict__ res_out)          // [B,N] (null for l=0)
{
  __shared__ float xb[N_];      // residual row (8 KB)
  __shared__ float2 kvA[N_];    // kv double buffer (16 KB each)
  __shared__ float2 kvB[N_];
  __shared__ float2 red[WAVES];

  const int bid = blockIdx.x;
  const int b = bid / CHUNKS;
  const int chunk = bid % CHUNKS;
  const int i0 = chunk * RPB;
  const int tid = threadIdx.x;
  const int wave = tid >> 6;
  const int lane = tid & 63;
  const int irow = i0 + wave * RPW;   // this wave's first row

  // ---- Stage cur row into LDS (folding previous LN if present) ----
  if (a_prev == nullptr) {
    for (int j = tid; j < N_; j += THREADS) xb[j] = res_in[b * N_ + j];
  } else {
    float2 p0 = part_prev[b * CHUNKS + lane];
    float2 p1 = part_prev[b * CHUNKS + 64 + lane];
    float s1 = p0.x + p1.x;
    float s2 = p0.y + p1.y;
#pragma unroll
    for (int off = 32; off; off >>= 1) {
      s1 += __shfl_xor(s1, off);
      s2 += __shfl_xor(s2, off);
    }
    const float mean = s1 * (1.f / N_);
    const float var = (s2 - s1 * mean) * (1.f / (N_ - 1));
    const float inv = 1.f / (sqrtf(var) + EPS_);
    for (int j = tid; j < N_; j += THREADS) {
      float r = res_in[b * N_ + j];
      float aj = a_prev[b * N_ + j];
      xb[j] = r + gamma[j] * (aj - mean) * inv + beta[j];
    }
  }
  __syncthreads();

  if (res_out != nullptr && tid < RPB)
    res_out[b * N_ + i0 + tid] = xb[i0 + tid];

  // ---- Per-layer register caches of xb ----
  float xj[SIT];
#pragma unroll
  for (int it = 0; it < SIT; ++it) xj[it] = xb[tid + it * THREADS];
  float xi[RPW];
#pragma unroll
  for (int r = 0; r < RPW; ++r) xi[r] = xb[irow + r];

  // ---- Prologue: stage head 0 ----
  float rk[SIT], rv[SIT];
#pragma unroll
  for (int it = 0; it < SIT; ++it) {
    const int jt = tid + it * THREADS;
    rk[it] = wk[jt];
    rv[it] = wv[jt];
  }
  float qn[RPW];
#pragma unroll
  for (int r = 0; r < RPW; ++r) qn[r] = xi[r] * wq[irow + r];

  float2* cur = kvA;
  float2* nxt = kvB;
#pragma unroll
  for (int it = 0; it < SIT; ++it) {
    const int jt = tid + it * THREADS;
    cur[jt] = make_float2(xj[it] * rk[it] * LOG2E, xj[it] * rv[it]);
  }

  float acc[RPW];
#pragma unroll
  for (int r = 0; r < RPW; ++r) acc[r] = 0.f;
  __syncthreads();

  // ---- Pipelined head loop: one barrier per head ----
  for (int h = 0; h < H_; ++h) {
    float q[RPW];
#pragma unroll
    for (int r = 0; r < RPW; ++r) q[r] = qn[r];
    const float w0h = w0[h];

    // (1) issue next head's global loads (latency hides under inner loop)
    if (h + 1 < H_) {
#pragma unroll
      for (int it = 0; it < SIT; ++it) {
        const int jt = tid + it * THREADS;
        rk[it] = wk[(h + 1) * N_ + jt];
        rv[it] = wv[(h + 1) * N_ + jt];
      }
#pragma unroll
      for (int r = 0; r < RPW; ++r)
        qn[r] = xi[r] * wq[(h + 1) * N_ + irow + r];
    }

    // (2) inner exp loop on current buffer
    float d[RPW], n[RPW];
#pragma unroll
    for (int r = 0; r < RPW; ++r) { d[r] = 0.f; n[r] = 0.f; }
#pragma unroll
    for (int it = 0; it < ITERS; ++it) {
      float2 kvj = cur[it * 64 + lane];
#pragma unroll
      for (int r = 0; r < RPW; ++r) {
        float e = __builtin_amdgcn_exp2f(q[r] * kvj.x);
        d[r] += e;
        n[r] = fmaf(e, kvj.y, n[r]);
      }
    }

    // (3) write next head's kv into the other buffer
    if (h + 1 < H_) {
#pragma unroll
      for (int it = 0; it < SIT; ++it) {
        const int jt = tid + it * THREADS;
        nxt[jt] = make_float2(xj[it] * rk[it] * LOG2E, xj[it] * rv[it]);
      }
    }

    // (4) reduce + accumulate
#pragma unroll
    for (int r = 0; r < RPW; ++r) {
      float dd = d[r], nn = n[r];
#pragma unroll
      for (int off = 32; off; off >>= 1) {
        dd += __shfl_xor(dd, off);
        nn += __shfl_xor(nn, off);
      }
      float2 kvi = cur[irow + r];
      float ed = __builtin_amdgcn_exp2f(q[r] * kvi.x);  // diagonal term
      acc[r] = fmaf(w0h, (nn - ed * kvi.y) * __builtin_amdgcn_rcpf(dd), acc[r]);
    }

    // (5) one barrier: nxt fully written, cur free for overwrite next head
    __syncthreads();
    float2* t = cur; cur = nxt; nxt = t;
  }

  // ---- Outputs: a_out chunk + (sum,sumsq) partial ----
  if (lane == 0) {
    float s1 = 0.f, s2 = 0.f;
#pragma unroll
    for (int r = 0; r < RPW; ++r) {
      a_out[b * N_ + irow + r] = acc[r];
      s1 += acc[r];
      s2 = fmaf(acc[r], acc[r], s2);
    }
    red[wave] = make_float2(s1, s2);
  }
  __syncthreads();
  if (tid == 0) {
    float2 t = red[0];
#pragma unroll
    for (int w = 1; w < WAVES; ++w) {
      t.x += red[w].x;
      t.y += red[w].y;
    }
    part_out[b * CHUNKS + chunk] = t;
  }
}

// out[b,:] = res_in + gamma*(a-mean)/(sqrt(var_unbiased)+eps) + beta
__global__ __launch_bounds__(256) void final_ln_kernel(
    const float* __restrict__ res_in, const float* __restrict__ a_prev,
    const float2* __restrict__ part_prev, const float* __restrict__ gamma,
    const float* __restrict__ beta, float* __restrict__ out)
{
  const int b = blockIdx.x;
  const int tid = threadIdx.x;
  const int lane = tid & 63;

  float2 p0 = part_prev[b * CHUNKS + lane];
  float2 p1 = part_prev[b * CHUNKS + 64 + lane];
  float s1 = p0.x + p1.x;
  float s2 = p0.y + p1.y;
#pragma unroll
  for (int off = 32; off; off >>= 1) {
    s1 += __shfl_xor(s1, off);
    s2 += __shfl_xor(s2, off);
  }
  const float mean = s1 * (1.f / N_);
  const float var = (s2 - s1 * mean) * (1.f / (N_ - 1));
  const float inv = 1.f / (sqrtf(var) + EPS_);

  for (int j = tid; j < N_; j += 256) {
    out[b * N_ + j] =
        res_in[b * N_ + j] + gamma[j] * (a_prev[b * N_ + j] - mean) * inv + beta[j];
  }
}

extern "C" void kernel_launch(void* const* d_in, const int* in_sizes, int n_in,
                              void* d_out, int out_size, void* d_ws, size_t ws_size,
                              hipStream_t stream) {
  const float* x     = (const float*)d_in[0];
  const float* WQ    = (const float*)d_in[1];  // [L,H,N]
  const float* WK    = (const float*)d_in[2];
  const float* WV    = (const float*)d_in[3];
  const float* W0    = (const float*)d_in[4];  // [L,H]
  const float* gamma = (const float*)d_in[5];
  const float* beta  = (const float*)d_in[6];
  float* out = (float*)d_out;

  float* ws = (float*)d_ws;
  float* a0 = ws;                 // [B,N]
  float* a1 = ws + 8192;          // [B,N]
  float* a2 = ws + 16384;         // [B,N]
  float* res1 = ws + 24576;       // [B,N]
  float* res2 = ws + 32768;       // [B,N]
  float2* p0 = (float2*)(ws + 40960);  // [B,CHUNKS]
  float2* p1 = (float2*)(ws + 43008);  // [B,CHUNKS]
  float2* p2 = (float2*)(ws + 45056);  // [B,CHUNKS]

  const int G = B_ * CHUNKS;  // 512 blocks

  attn_layer_kernel<<<G, THREADS, 0, stream>>>(
      x, nullptr, nullptr, gamma, beta,
      WQ, WK, WV, W0, a0, p0, nullptr);
  attn_layer_kernel<<<G, THREADS, 0, stream>>>(
      x, a0, p0, gamma, beta,
      WQ + H_ * N_, WK + H_ * N_, WV + H_ * N_, W0 + H_, a1, p1, res1);
  attn_layer_kernel<<<G, THREADS, 0, stream>>>(
      res1, a1, p1, gamma, beta,
      WQ + 2 * H_ * N_, WK + 2 * H_ * N_, WV + 2 * H_ * N_, W0 + 2 * H_, a2, p2, res2);
  final_ln_kernel<<<B_, 256, 0, stream>>>(res2, a2, p2, gamma, beta, out);
}